// Round 1
// baseline (564.487 us; speedup 1.0000x reference)
//
#include <hip/hip_runtime.h>
#include <hip/hip_bf16.h>

#define NN 100000
#define NE 1600000
#define KF 128     // IN_FEATS
#define CT 256     // NUM_HEADS*OUT_FEATS
#define NH 8

__device__ __forceinline__ float bf2f(unsigned short u) {
  union { unsigned int i; float f; } x; x.i = ((unsigned int)u) << 16; return x.f;
}

// ---------------- K1: ft = feat @ W (fp32 acc, bf16 store) + el/er epilogue ----------------
// block = 256 threads, tile = 64 rows x 256 cols. Thread: 8 rows x 8 cols.
__global__ __launch_bounds__(256) void k_gemm(
    const float* __restrict__ feat, const float* __restrict__ W,
    const float* __restrict__ attn_l, const float* __restrict__ attn_r,
    unsigned short* __restrict__ ftb, float* __restrict__ el, float* __restrict__ er)
{
  __shared__ float fs[64][128];
  const int tid = threadIdx.x;
  const int row0 = blockIdx.x * 64;
  // stage feat tile (coalesced float4)
  for (int i = tid; i < 64 * 32; i += 256) {
    int r = i >> 5, c4 = i & 31;
    int gr = row0 + r;
    float4 v = make_float4(0.f, 0.f, 0.f, 0.f);
    if (gr < NN) v = *(const float4*)(feat + (size_t)gr * KF + c4 * 4);
    *(float4*)(&fs[r][c4 * 4]) = v;
  }
  __syncthreads();
  const int rowg = tid >> 5;   // 0..7
  const int colg = tid & 31;   // 0..31
  const int c0 = colg * 8;
  float acc[8][8];
#pragma unroll
  for (int r = 0; r < 8; r++)
#pragma unroll
    for (int c = 0; c < 8; c++) acc[r][c] = 0.f;

  for (int k = 0; k < KF; k += 4) {
    float w[4][8];
#pragma unroll
    for (int kk = 0; kk < 4; kk++) {
      float4 a0 = *(const float4*)(W + (k + kk) * CT + c0);
      float4 a1 = *(const float4*)(W + (k + kk) * CT + c0 + 4);
      w[kk][0] = a0.x; w[kk][1] = a0.y; w[kk][2] = a0.z; w[kk][3] = a0.w;
      w[kk][4] = a1.x; w[kk][5] = a1.y; w[kk][6] = a1.z; w[kk][7] = a1.w;
    }
#pragma unroll
    for (int r = 0; r < 8; r++) {
      float4 f = *(const float4*)(&fs[rowg * 8 + r][k]);
#pragma unroll
      for (int c = 0; c < 8; c++)
        acc[r][c] += f.x * w[0][c] + f.y * w[1][c] + f.z * w[2][c] + f.w * w[3][c];
    }
  }

  // store ft as bf16 (manual RNE)
#pragma unroll
  for (int r = 0; r < 8; r++) {
    int gr = row0 + rowg * 8 + r;
    if (gr < NN) {
      unsigned short tmp[8];
#pragma unroll
      for (int c = 0; c < 8; c++) {
        unsigned int b = __float_as_uint(acc[r][c]);
        b += 0x7fffu + ((b >> 16) & 1u);
        tmp[c] = (unsigned short)(b >> 16);
      }
      *(ushort4*)(ftb + (size_t)gr * CT + c0)     = make_ushort4(tmp[0], tmp[1], tmp[2], tmp[3]);
      *(ushort4*)(ftb + (size_t)gr * CT + c0 + 4) = make_ushort4(tmp[4], tmp[5], tmp[6], tmp[7]);
    }
  }

  // el/er epilogue: head h = colg>>2, within-head offset = (colg&3)*8
  const int h = colg >> 2;
  const int doff = (colg & 3) * 8;
  float al[8], ar[8];
#pragma unroll
  for (int c = 0; c < 8; c++) {
    al[c] = attn_l[h * 32 + doff + c];
    ar[c] = attn_r[h * 32 + doff + c];
  }
#pragma unroll
  for (int r = 0; r < 8; r++) {
    float pl = 0.f, pr = 0.f;
#pragma unroll
    for (int c = 0; c < 8; c++) { pl += acc[r][c] * al[c]; pr += acc[r][c] * ar[c]; }
    pl += __shfl_xor(pl, 1); pl += __shfl_xor(pl, 2);
    pr += __shfl_xor(pr, 1); pr += __shfl_xor(pr, 2);
    if ((colg & 3) == 0) {
      int gr = row0 + rowg * 8 + r;
      if (gr < NN) { el[gr * NH + h] = pl; er[gr * NH + h] = pr; }
    }
  }
}

// ---------------- K3: in-degree histogram ----------------
__global__ void k_hist(const int* __restrict__ dst, int* __restrict__ cnt) {
  int e = blockIdx.x * 256 + threadIdx.x;
  if (e < NE) atomicAdd(&cnt[dst[e]], 1);
}

// ---------------- K4: single-block exclusive scan over cnt -> off, cur ----------------
__global__ __launch_bounds__(1024) void k_scan(const int* __restrict__ cnt,
                                               int* __restrict__ off, int* __restrict__ cur, int n) {
  __shared__ int s_wsum[16];
  __shared__ int s_carry;
  const int tid = threadIdx.x;
  const int lane = tid & 63, wid = tid >> 6;
  if (tid == 0) s_carry = 0;
  __syncthreads();
  for (int base = 0; base < n; base += 1024) {
    int i = base + tid;
    int x = (i < n) ? cnt[i] : 0;
    int v = x;
#pragma unroll
    for (int d = 1; d < 64; d <<= 1) { int t = __shfl_up(v, d); if (lane >= d) v += t; }
    if (lane == 63) s_wsum[wid] = v;
    __syncthreads();
    if (tid < 16) {
      int s = s_wsum[tid];
#pragma unroll
      for (int d = 1; d < 16; d <<= 1) { int t = __shfl_up(s, d); if (tid >= d) s += t; }
      s_wsum[tid] = s;
    }
    __syncthreads();
    int pre = s_carry + (wid > 0 ? s_wsum[wid - 1] : 0);
    if (i < n) { int excl = pre + v - x; off[i] = excl; cur[i] = excl; }
    int total = s_carry + s_wsum[15];
    __syncthreads();
    if (tid == 0) s_carry = total;
    __syncthreads();
  }
  if (tid == 0) off[n] = s_carry;
}

// ---------------- K5: scatter edges into CSR ----------------
__global__ void k_scatter(const int* __restrict__ src, const int* __restrict__ dst,
                          int* __restrict__ cur, int* __restrict__ csr_src, int* __restrict__ csr_eid) {
  int e = blockIdx.x * 256 + threadIdx.x;
  if (e < NE) {
    int d = dst[e];
    int p = atomicAdd(&cur[d], 1);
    csr_src[p] = src[e];
    csr_eid[p] = e;
  }
}

// ---------------- K6: per-node softmax + aggregation (1 wave = 1 node) ----------------
__global__ __launch_bounds__(256) void k_edge(
    const int* __restrict__ off, const int* __restrict__ csr_src, const int* __restrict__ csr_eid,
    const float* __restrict__ el, const float* __restrict__ er,
    const unsigned short* __restrict__ ftb, const float* __restrict__ bias,
    float* __restrict__ hout, float* __restrict__ attn_out)
{
  const int wid = threadIdx.x >> 6;
  const int lane = threadIdx.x & 63;
  const int n = blockIdx.x * 4 + wid;
  if (n >= NN) return;
  const int beg = off[n], end = off[n + 1];
  const int h = lane & 7;      // head for softmax phase
  const int eg = lane >> 3;    // edge-in-group for softmax phase
  const float er_v = er[n * NH + h];

  // pass 1: softmax denominator per head (exact, no atomics)
  float sum = 0.f;
  for (int g = beg; g < end; g += 8) {
    int s = g + eg;
    float w = 0.f;
    if (s < end) {
      int sn = csr_src[s];
      float e = el[sn * NH + h] + er_v;
      e = (e > 0.f) ? e : 0.2f * e;
      w = expf(e);
    }
    w += __shfl_xor(w, 8); w += __shfl_xor(w, 16); w += __shfl_xor(w, 32);
    sum += w;
  }
  const float inv = (sum > 0.f) ? 1.f / sum : 0.f;

  // pass 2: attn write + message aggregation.
  // lane owns cols lane*4..lane*4+3 of the 256-wide ft row: h_own = lane>>3, d = (lane&7)*4
  const int h_own = lane >> 3;
  float acc0 = 0.f, acc1 = 0.f, acc2 = 0.f, acc3 = 0.f;
  for (int g = beg; g < end; g += 8) {
    int s = g + eg;
    float a = 0.f;
    int sn = 0;
    if (s < end) {
      sn = csr_src[s];
      int eid = csr_eid[s];
      float e = el[sn * NH + h] + er_v;
      e = (e > 0.f) ? e : 0.2f * e;
      a = expf(e) * inv;
      attn_out[(size_t)eid * NH + h] = a;
    }
    int m = end - g; if (m > 8) m = 8;
    for (int j = 0; j < m; ++j) {
      float aj = __shfl(a, j * 8 + h_own);
      int snj = __shfl(sn, j * 8);
      ushort4 u = *(const ushort4*)(ftb + (size_t)snj * CT + lane * 4);
      acc0 += bf2f(u.x) * aj;
      acc1 += bf2f(u.y) * aj;
      acc2 += bf2f(u.z) * aj;
      acc3 += bf2f(u.w) * aj;
    }
  }

  // reduce over heads (lanes differing in bits 3..5 share the same d)
#pragma unroll
  for (int mks = 8; mks <= 32; mks <<= 1) {
    acc0 += __shfl_xor(acc0, mks);
    acc1 += __shfl_xor(acc1, mks);
    acc2 += __shfl_xor(acc2, mks);
    acc3 += __shfl_xor(acc3, mks);
  }
  if (lane < 8) {
    float b0 = 0.f, b1 = 0.f, b2 = 0.f, b3 = 0.f;
#pragma unroll
    for (int hh = 0; hh < NH; hh++) {
      const float* bp = bias + hh * 32 + lane * 4;
      b0 += bp[0]; b1 += bp[1]; b2 += bp[2]; b3 += bp[3];
    }
    float4 o;
    o.x = (acc0 + b0) * 0.125f;
    o.y = (acc1 + b1) * 0.125f;
    o.z = (acc2 + b2) * 0.125f;
    o.w = (acc3 + b3) * 0.125f;
    *(float4*)(hout + (size_t)n * 32 + lane * 4) = o;
  }
}

extern "C" void kernel_launch(void* const* d_in, const int* in_sizes, int n_in,
                              void* d_out, int out_size, void* d_ws, size_t ws_size,
                              hipStream_t stream) {
  const float* feat   = (const float*)d_in[0];
  const int*   src    = (const int*)d_in[1];
  const int*   dst    = (const int*)d_in[2];
  const float* W      = (const float*)d_in[3];
  const float* attn_l = (const float*)d_in[4];
  const float* attn_r = (const float*)d_in[5];
  const float* bias   = (const float*)d_in[6];

  char* ws = (char*)d_ws;
  unsigned short* ftb = (unsigned short*)ws;                 // NN*CT bf16 = 51.2 MB
  float* el  = (float*)(ws + (size_t)NN * CT * 2);           // NN*8 f32
  float* er  = el + (size_t)NN * NH;                         // NN*8 f32
  int* cnt   = (int*)(er + (size_t)NN * NH);                 // NN
  int* off   = cnt + NN;                                     // NN+1
  int* cur   = off + NN + 1;                                 // NN
  int* csr_src = cur + NN;                                   // NE
  int* csr_eid = csr_src + NE;                               // NE

  float* hout     = (float*)d_out;                           // NN*32
  float* attn_out = hout + (size_t)NN * 32;                  // NE*8

  k_gemm<<<(NN + 63) / 64, 256, 0, stream>>>(feat, W, attn_l, attn_r, ftb, el, er);
  hipMemsetAsync(cnt, 0, NN * sizeof(int), stream);
  k_hist<<<(NE + 255) / 256, 256, 0, stream>>>(dst, cnt);
  k_scan<<<1, 1024, 0, stream>>>(cnt, off, cur, NN);
  k_scatter<<<(NE + 255) / 256, 256, 0, stream>>>(src, dst, cur, csr_src, csr_eid);
  k_edge<<<NN / 4, 256, 0, stream>>>(off, csr_src, csr_eid, el, er, ftb, bias, hout, attn_out);
}

// Round 2
// 429.885 us; speedup vs baseline: 1.3131x; 1.3131x over previous
//
#include <hip/hip_runtime.h>
#include <hip/hip_bf16.h>

#define NN 100000
#define NE 1600000
#define KF 128     // IN_FEATS
#define CT 256     // NUM_HEADS*OUT_FEATS
#define NH 8

typedef __attribute__((ext_vector_type(8))) short short8;
typedef __attribute__((ext_vector_type(4))) float f32x4;

__device__ __forceinline__ float bf2f(unsigned short u) {
  union { unsigned int i; float f; } x; x.i = ((unsigned int)u) << 16; return x.f;
}
__device__ __forceinline__ unsigned short f2bf(float f) {
  unsigned int b = __float_as_uint(f);
  b += 0x7fffu + ((b >> 16) & 1u);
  return (unsigned short)(b >> 16);
}

// ---------------- K0: W (128x256 f32) -> Wt (256x128 bf16, transposed) ----------------
__global__ void k_wconv(const float* __restrict__ W, unsigned short* __restrict__ Wt) {
  int i = blockIdx.x * 256 + threadIdx.x;
  if (i < KF * CT) {
    int k = i >> 8, c = i & 255;
    Wt[c * KF + k] = f2bf(W[i]);
  }
}

// ---------------- K1: ft = feat @ W via bf16 MFMA ----------------
// block = 256 (4 waves), tile = 64 rows x 256 cols; wave w owns cols w*64..w*64+63.
__global__ __launch_bounds__(256) void k_gemm(
    const float* __restrict__ feat, const unsigned short* __restrict__ Wt,
    unsigned short* __restrict__ ftb)
{
  __shared__ unsigned short fs[64][136];  // +8 pad: 272B row stride -> 2-way bank alias (free)
  const int tid = threadIdx.x;
  const int lane = tid & 63, w = tid >> 6;
  const int row0 = blockIdx.x * 64;

  // stage feat tile, convert f32 -> bf16
  for (int i = tid; i < 64 * 32; i += 256) {
    int r = i >> 5, c4 = (i & 31) * 4;
    int gr = row0 + r;
    float4 v = make_float4(0.f, 0.f, 0.f, 0.f);
    if (gr < NN) v = *(const float4*)(feat + (size_t)gr * KF + c4);
    ushort4 u = make_ushort4(f2bf(v.x), f2bf(v.y), f2bf(v.z), f2bf(v.w));
    *(ushort4*)(&fs[r][c4]) = u;
  }

  // preload all 16 B fragments (constant per wave) from global bf16 Wt
  const int bc = lane & 15;
  const int bk = (lane >> 4) * 8;
  short8 bfrag[4][4];  // [kstep][n]
#pragma unroll
  for (int ks = 0; ks < 4; ks++)
#pragma unroll
    for (int n = 0; n < 4; n++) {
      const unsigned short* p = Wt + (size_t)(w * 64 + n * 16 + bc) * KF + ks * 32 + bk;
      bfrag[ks][n] = *(const short8*)p;
    }

  __syncthreads();

  f32x4 acc[4][4];
#pragma unroll
  for (int m = 0; m < 4; m++)
#pragma unroll
    for (int n = 0; n < 4; n++) acc[m][n] = (f32x4){0.f, 0.f, 0.f, 0.f};

#pragma unroll
  for (int ks = 0; ks < 4; ks++) {
    short8 af[4];
#pragma unroll
    for (int m = 0; m < 4; m++)
      af[m] = *(const short8*)(&fs[m * 16 + bc][ks * 32 + bk]);
#pragma unroll
    for (int m = 0; m < 4; m++)
#pragma unroll
      for (int n = 0; n < 4; n++)
        acc[m][n] = __builtin_amdgcn_mfma_f32_16x16x32_bf16(af[m], bfrag[ks][n], acc[m][n], 0, 0, 0);
  }

  // write ftb: row = (lane>>4)*4 + reg, col = n*16 + (lane&15)
  const int rbase = (lane >> 4) * 4;
#pragma unroll
  for (int m = 0; m < 4; m++) {
#pragma unroll
    for (int r = 0; r < 4; r++) {
      int gr = row0 + m * 16 + rbase + r;
      if (gr < NN) {
        unsigned short* op = ftb + (size_t)gr * CT + w * 64 + bc;
#pragma unroll
        for (int n = 0; n < 4; n++) op[n * 16] = f2bf(acc[m][n][r]);
      }
    }
  }
}

// ---------------- K2: el/er from bf16 ft ----------------
__global__ __launch_bounds__(256) void k_elr(
    const unsigned short* __restrict__ ftb,
    const float* __restrict__ attn_l, const float* __restrict__ attn_r,
    float* __restrict__ el, float* __restrict__ er)
{
  const int wid = threadIdx.x >> 6, lane = threadIdx.x & 63;
  const int n = blockIdx.x * 4 + wid;
  if (n >= NN) return;
  const int h = lane >> 3;
  const int base = h * 32 + (lane & 7) * 4;
  float al[4], ar[4];
#pragma unroll
  for (int j = 0; j < 4; j++) { al[j] = attn_l[base + j]; ar[j] = attn_r[base + j]; }
  ushort4 u = *(const ushort4*)(ftb + (size_t)n * CT + lane * 4);
  float f0 = bf2f(u.x), f1 = bf2f(u.y), f2 = bf2f(u.z), f3 = bf2f(u.w);
  float pl = f0 * al[0] + f1 * al[1] + f2 * al[2] + f3 * al[3];
  float pr = f0 * ar[0] + f1 * ar[1] + f2 * ar[2] + f3 * ar[3];
  pl += __shfl_xor(pl, 1); pl += __shfl_xor(pl, 2); pl += __shfl_xor(pl, 4);
  pr += __shfl_xor(pr, 1); pr += __shfl_xor(pr, 2); pr += __shfl_xor(pr, 4);
  if ((lane & 7) == 0) { el[n * NH + h] = pl; er[n * NH + h] = pr; }
}

// ---------------- K3: in-degree histogram ----------------
__global__ void k_hist(const int* __restrict__ dst, int* __restrict__ cnt) {
  int e = blockIdx.x * 256 + threadIdx.x;
  if (e < NE) atomicAdd(&cnt[dst[e]], 1);
}

// ---------------- K4a: per-block sums ----------------
__global__ __launch_bounds__(1024) void k_scan1(const int* __restrict__ cnt, int* __restrict__ bsum) {
  __shared__ int ws[16];
  const int tid = threadIdx.x, lane = tid & 63, wid = tid >> 6;
  int i = blockIdx.x * 1024 + tid;
  int x = (i < NN) ? cnt[i] : 0;
#pragma unroll
  for (int d = 1; d < 64; d <<= 1) x += __shfl_xor(x, d);
  if (lane == 0) ws[wid] = x;
  __syncthreads();
  if (tid == 0) {
    int s = 0;
#pragma unroll
    for (int k = 0; k < 16; k++) s += ws[k];
    bsum[blockIdx.x] = s;
  }
}

// ---------------- K4b: scan the 98 block sums ----------------
__global__ void k_scan2(const int* __restrict__ bsum, int* __restrict__ bexc, int nb) {
  __shared__ int wsum[2];
  const int tid = threadIdx.x, lane = tid & 63, wid = tid >> 6;
  int x = (tid < nb) ? bsum[tid] : 0;
  int v = x;
#pragma unroll
  for (int d = 1; d < 64; d <<= 1) { int t = __shfl_up(v, d); if (lane >= d) v += t; }
  if (lane == 63) wsum[wid] = v;
  __syncthreads();
  int pre = (wid > 0) ? wsum[0] : 0;
  if (tid < nb) bexc[tid] = pre + v - x;
}

// ---------------- K4c: apply offsets ----------------
__global__ __launch_bounds__(1024) void k_scan3(const int* __restrict__ cnt, const int* __restrict__ bexc,
                                                int* __restrict__ off, int* __restrict__ cur) {
  __shared__ int ws[16];
  const int tid = threadIdx.x, lane = tid & 63, wid = tid >> 6;
  int i = blockIdx.x * 1024 + tid;
  int x = (i < NN) ? cnt[i] : 0;
  int v = x;
#pragma unroll
  for (int d = 1; d < 64; d <<= 1) { int t = __shfl_up(v, d); if (lane >= d) v += t; }
  if (lane == 63) ws[wid] = v;
  __syncthreads();
  if (tid < 16) {
    int s = ws[tid];
#pragma unroll
    for (int d = 1; d < 16; d <<= 1) { int t = __shfl_up(s, d); if (tid >= d) s += t; }
    ws[tid] = s;
  }
  __syncthreads();
  int pre = bexc[blockIdx.x] + (wid > 0 ? ws[wid - 1] : 0);
  if (i < NN) { int e = pre + v - x; off[i] = e; cur[i] = e; }
  if (blockIdx.x == 0 && tid == 0) off[NN] = NE;
}

// ---------------- K5: scatter edges into CSR ----------------
__global__ void k_scatter(const int* __restrict__ src, const int* __restrict__ dst,
                          int* __restrict__ cur, int* __restrict__ csr_src, int* __restrict__ csr_eid) {
  int e = blockIdx.x * 256 + threadIdx.x;
  if (e < NE) {
    int d = dst[e];
    int p = atomicAdd(&cur[d], 1);
    csr_src[p] = src[e];
    csr_eid[p] = e;
  }
}

// ---------------- K6: per-node softmax + aggregation (1 wave = 1 node) ----------------
__global__ __launch_bounds__(256) void k_edge(
    const int* __restrict__ off, const int* __restrict__ csr_src, const int* __restrict__ csr_eid,
    const float* __restrict__ el, const float* __restrict__ er,
    const unsigned short* __restrict__ ftb, const float* __restrict__ bias,
    float* __restrict__ hout, float* __restrict__ attn_out)
{
  const int wid = threadIdx.x >> 6;
  const int lane = threadIdx.x & 63;
  const int n = blockIdx.x * 4 + wid;
  if (n >= NN) return;
  const int beg = off[n], end = off[n + 1];
  const int h = lane & 7;
  const int eg = lane >> 3;
  const float er_v = er[n * NH + h];

  float sum = 0.f;
  for (int g = beg; g < end; g += 8) {
    int s = g + eg;
    float w = 0.f;
    if (s < end) {
      int sn = csr_src[s];
      float e = el[sn * NH + h] + er_v;
      e = (e > 0.f) ? e : 0.2f * e;
      w = expf(e);
    }
    w += __shfl_xor(w, 8); w += __shfl_xor(w, 16); w += __shfl_xor(w, 32);
    sum += w;
  }
  const float inv = (sum > 0.f) ? 1.f / sum : 0.f;

  const int h_own = lane >> 3;
  float acc0 = 0.f, acc1 = 0.f, acc2 = 0.f, acc3 = 0.f;
  for (int g = beg; g < end; g += 8) {
    int s = g + eg;
    float a = 0.f;
    int sn = 0;
    if (s < end) {
      sn = csr_src[s];
      int eid = csr_eid[s];
      float e = el[sn * NH + h] + er_v;
      e = (e > 0.f) ? e : 0.2f * e;
      a = expf(e) * inv;
      attn_out[(size_t)eid * NH + h] = a;
    }
    int m = end - g; if (m > 8) m = 8;
    for (int j = 0; j < m; ++j) {
      float aj = __shfl(a, j * 8 + h_own);
      int snj = __shfl(sn, j * 8);
      ushort4 u = *(const ushort4*)(ftb + (size_t)snj * CT + lane * 4);
      acc0 += bf2f(u.x) * aj;
      acc1 += bf2f(u.y) * aj;
      acc2 += bf2f(u.z) * aj;
      acc3 += bf2f(u.w) * aj;
    }
  }

#pragma unroll
  for (int mks = 8; mks <= 32; mks <<= 1) {
    acc0 += __shfl_xor(acc0, mks);
    acc1 += __shfl_xor(acc1, mks);
    acc2 += __shfl_xor(acc2, mks);
    acc3 += __shfl_xor(acc3, mks);
  }
  if (lane < 8) {
    float b0 = 0.f, b1 = 0.f, b2 = 0.f, b3 = 0.f;
#pragma unroll
    for (int hh = 0; hh < NH; hh++) {
      const float* bp = bias + hh * 32 + lane * 4;
      b0 += bp[0]; b1 += bp[1]; b2 += bp[2]; b3 += bp[3];
    }
    float4 o;
    o.x = (acc0 + b0) * 0.125f;
    o.y = (acc1 + b1) * 0.125f;
    o.z = (acc2 + b2) * 0.125f;
    o.w = (acc3 + b3) * 0.125f;
    *(float4*)(hout + (size_t)n * 32 + lane * 4) = o;
  }
}

extern "C" void kernel_launch(void* const* d_in, const int* in_sizes, int n_in,
                              void* d_out, int out_size, void* d_ws, size_t ws_size,
                              hipStream_t stream) {
  const float* feat   = (const float*)d_in[0];
  const int*   src    = (const int*)d_in[1];
  const int*   dst    = (const int*)d_in[2];
  const float* W      = (const float*)d_in[3];
  const float* attn_l = (const float*)d_in[4];
  const float* attn_r = (const float*)d_in[5];
  const float* bias   = (const float*)d_in[6];

  char* ws = (char*)d_ws;
  unsigned short* ftb = (unsigned short*)ws;                 // NN*CT bf16 = 51.2 MB
  float* el  = (float*)(ws + (size_t)NN * CT * 2);           // NN*8 f32
  float* er  = el + (size_t)NN * NH;                         // NN*8 f32
  int* cnt   = (int*)(er + (size_t)NN * NH);                 // NN
  int* off   = cnt + NN;                                     // NN+1
  int* cur   = off + NN + 1;                                 // NN
  int* csr_src = cur + NN;                                   // NE
  int* csr_eid = csr_src + NE;                               // NE
  unsigned short* Wt = (unsigned short*)(csr_eid + NE);      // 256*128 bf16
  int* bsum = (int*)(Wt + CT * KF);                          // 98
  int* bexc = bsum + 128;                                    // 98

  float* hout     = (float*)d_out;                           // NN*32
  float* attn_out = hout + (size_t)NN * 32;                  // NE*8

  const int NB = (NN + 1023) / 1024;  // 98

  k_wconv<<<(KF * CT + 255) / 256, 256, 0, stream>>>(W, Wt);
  k_gemm<<<(NN + 63) / 64, 256, 0, stream>>>(feat, Wt, ftb);
  k_elr<<<(NN + 3) / 4, 256, 0, stream>>>(ftb, attn_l, attn_r, el, er);
  hipMemsetAsync(cnt, 0, NN * sizeof(int), stream);
  k_hist<<<(NE + 255) / 256, 256, 0, stream>>>(dst, cnt);
  k_scan1<<<NB, 1024, 0, stream>>>(cnt, bsum);
  k_scan2<<<1, 128, 0, stream>>>(bsum, bexc, NB);
  k_scan3<<<NB, 1024, 0, stream>>>(cnt, bexc, off, cur);
  k_scatter<<<(NE + 255) / 256, 256, 0, stream>>>(src, dst, cur, csr_src, csr_eid);
  k_edge<<<(NN + 3) / 4, 256, 0, stream>>>(off, csr_src, csr_eid, el, er, ftb, bias, hout, attn_out);
}

// Round 3
// 413.296 us; speedup vs baseline: 1.3658x; 1.0401x over previous
//
#include <hip/hip_runtime.h>
#include <hip/hip_bf16.h>

#define NN 100000
#define NE 1600000
#define KF 128     // IN_FEATS
#define CT 256     // NUM_HEADS*OUT_FEATS
#define NH 8

typedef __attribute__((ext_vector_type(8))) short short8;
typedef __attribute__((ext_vector_type(4))) float f32x4;

__device__ __forceinline__ float bf2f(unsigned short u) {
  union { unsigned int i; float f; } x; x.i = ((unsigned int)u) << 16; return x.f;
}
__device__ __forceinline__ unsigned short f2bf(float f) {
  unsigned int b = __float_as_uint(f);
  b += 0x7fffu + ((b >> 16) & 1u);
  return (unsigned short)(b >> 16);
}

// ---------------- K0: W (128x256 f32) -> Wt (256x128 bf16, transposed) ----------------
__global__ void k_wconv(const float* __restrict__ W, unsigned short* __restrict__ Wt) {
  int i = blockIdx.x * 256 + threadIdx.x;
  if (i < KF * CT) {
    int k = i >> 8, c = i & 255;
    Wt[c * KF + k] = f2bf(W[i]);
  }
}

// ---------------- K1: ft = feat @ W via bf16 MFMA, fused el/er epilogue ----------------
// block = 256 (4 waves), tile = 64 rows x 256 cols; wave w owns cols w*64..w*64+63.
__global__ __launch_bounds__(256) void k_gemm(
    const float* __restrict__ feat, const unsigned short* __restrict__ Wt,
    const float* __restrict__ attn_l, const float* __restrict__ attn_r,
    unsigned short* __restrict__ ftb, float* __restrict__ el, float* __restrict__ er)
{
  __shared__ unsigned short fs[64][136];  // +8 pad: 272B stride -> 2-way alias (free)
  const int tid = threadIdx.x;
  const int lane = tid & 63, w = tid >> 6;
  const int row0 = blockIdx.x * 64;

  for (int i = tid; i < 64 * 32; i += 256) {
    int r = i >> 5, c4 = (i & 31) * 4;
    int gr = row0 + r;
    float4 v = make_float4(0.f, 0.f, 0.f, 0.f);
    if (gr < NN) v = *(const float4*)(feat + (size_t)gr * KF + c4);
    *(ushort4*)(&fs[r][c4]) = make_ushort4(f2bf(v.x), f2bf(v.y), f2bf(v.z), f2bf(v.w));
  }

  const int bc = lane & 15;
  const int bk = (lane >> 4) * 8;
  short8 bfrag[4][4];
#pragma unroll
  for (int ks = 0; ks < 4; ks++)
#pragma unroll
    for (int n = 0; n < 4; n++)
      bfrag[ks][n] = *(const short8*)(Wt + (size_t)(w * 64 + n * 16 + bc) * KF + ks * 32 + bk);

  __syncthreads();

  f32x4 acc[4][4];
#pragma unroll
  for (int m = 0; m < 4; m++)
#pragma unroll
    for (int n = 0; n < 4; n++) acc[m][n] = (f32x4){0.f, 0.f, 0.f, 0.f};

#pragma unroll
  for (int ks = 0; ks < 4; ks++) {
    short8 af[4];
#pragma unroll
    for (int m = 0; m < 4; m++)
      af[m] = *(const short8*)(&fs[m * 16 + bc][ks * 32 + bk]);
#pragma unroll
    for (int m = 0; m < 4; m++)
#pragma unroll
      for (int n = 0; n < 4; n++)
        acc[m][n] = __builtin_amdgcn_mfma_f32_16x16x32_bf16(af[m], bfrag[ks][n], acc[m][n], 0, 0, 0);
  }

  const int rbase = (lane >> 4) * 4;

  // ftb store: row = m*16 + rbase + r, col = w*64 + n*16 + bc
#pragma unroll
  for (int m = 0; m < 4; m++) {
#pragma unroll
    for (int r = 0; r < 4; r++) {
      int gr = row0 + m * 16 + rbase + r;
      if (gr < NN) {
        unsigned short* op = ftb + (size_t)gr * CT + w * 64 + bc;
#pragma unroll
        for (int n = 0; n < 4; n++) op[n * 16] = f2bf(acc[m][n][r]);
      }
    }
  }

  // fused el/er: head 2w covers n=0,1; head 2w+1 covers n=2,3; attn_l flat layout == col index
  float al[4], ar[4];
#pragma unroll
  for (int n = 0; n < 4; n++) {
    al[n] = attn_l[w * 64 + n * 16 + bc];
    ar[n] = attn_r[w * 64 + n * 16 + bc];
  }
#pragma unroll
  for (int m = 0; m < 4; m++) {
#pragma unroll
    for (int r = 0; r < 4; r++) {
      float pl0 = acc[m][0][r] * al[0] + acc[m][1][r] * al[1];
      float pl1 = acc[m][2][r] * al[2] + acc[m][3][r] * al[3];
      float pr0 = acc[m][0][r] * ar[0] + acc[m][1][r] * ar[1];
      float pr1 = acc[m][2][r] * ar[2] + acc[m][3][r] * ar[3];
#pragma unroll
      for (int d = 1; d < 16; d <<= 1) {
        pl0 += __shfl_xor(pl0, d);
        pl1 += __shfl_xor(pl1, d);
        pr0 += __shfl_xor(pr0, d);
        pr1 += __shfl_xor(pr1, d);
      }
      if (bc == 0) {
        int gr = row0 + m * 16 + rbase + r;
        if (gr < NN) {
          *(float2*)(el + (size_t)gr * NH + 2 * w) = make_float2(pl0, pl1);
          *(float2*)(er + (size_t)gr * NH + 2 * w) = make_float2(pr0, pr1);
        }
      }
    }
  }
}

// ---------------- K3: in-degree histogram ----------------
__global__ void k_hist(const int* __restrict__ dst, int* __restrict__ cnt) {
  int e = blockIdx.x * 256 + threadIdx.x;
  if (e < NE) atomicAdd(&cnt[dst[e]], 1);
}

// ---------------- K4a: per-block sums ----------------
__global__ __launch_bounds__(1024) void k_scan1(const int* __restrict__ cnt, int* __restrict__ bsum) {
  __shared__ int ws[16];
  const int tid = threadIdx.x, lane = tid & 63, wid = tid >> 6;
  int i = blockIdx.x * 1024 + tid;
  int x = (i < NN) ? cnt[i] : 0;
#pragma unroll
  for (int d = 1; d < 64; d <<= 1) x += __shfl_xor(x, d);
  if (lane == 0) ws[wid] = x;
  __syncthreads();
  if (tid == 0) {
    int s = 0;
#pragma unroll
    for (int k = 0; k < 16; k++) s += ws[k];
    bsum[blockIdx.x] = s;
  }
}

// ---------------- K4b: scan block sums ----------------
__global__ void k_scan2(const int* __restrict__ bsum, int* __restrict__ bexc, int nb) {
  __shared__ int wsum[2];
  const int tid = threadIdx.x, lane = tid & 63, wid = tid >> 6;
  int x = (tid < nb) ? bsum[tid] : 0;
  int v = x;
#pragma unroll
  for (int d = 1; d < 64; d <<= 1) { int t = __shfl_up(v, d); if (lane >= d) v += t; }
  if (lane == 63) wsum[wid] = v;
  __syncthreads();
  int pre = (wid > 0) ? wsum[0] : 0;
  if (tid < nb) bexc[tid] = pre + v - x;
}

// ---------------- K4c: apply offsets ----------------
__global__ __launch_bounds__(1024) void k_scan3(const int* __restrict__ cnt, const int* __restrict__ bexc,
                                                int* __restrict__ off, int* __restrict__ cur) {
  __shared__ int ws[16];
  const int tid = threadIdx.x, lane = tid & 63, wid = tid >> 6;
  int i = blockIdx.x * 1024 + tid;
  int x = (i < NN) ? cnt[i] : 0;
  int v = x;
#pragma unroll
  for (int d = 1; d < 64; d <<= 1) { int t = __shfl_up(v, d); if (lane >= d) v += t; }
  if (lane == 63) ws[wid] = v;
  __syncthreads();
  if (tid < 16) {
    int s = ws[tid];
#pragma unroll
    for (int d = 1; d < 16; d <<= 1) { int t = __shfl_up(s, d); if (tid >= d) s += t; }
    ws[tid] = s;
  }
  __syncthreads();
  int pre = bexc[blockIdx.x] + (wid > 0 ? ws[wid - 1] : 0);
  if (i < NN) { int e = pre + v - x; off[i] = e; cur[i] = e; }
  if (blockIdx.x == 0 && tid == 0) off[NN] = NE;
}

// ---------------- K5: scatter edges into CSR (int2 = {src, eid}) ----------------
__global__ void k_scatter(const int* __restrict__ src, const int* __restrict__ dst,
                          int* __restrict__ cur, int2* __restrict__ csr_se) {
  int e = blockIdx.x * 256 + threadIdx.x;
  if (e < NE) {
    int d = dst[e];
    int p = atomicAdd(&cur[d], 1);
    csr_se[p] = make_int2(src[e], e);
  }
}

// ---------------- K6: per-node softmax + aggregation (1 wave = 1 node, 8-way MLP) ----------------
__global__ __launch_bounds__(256) void k_edge(
    const int* __restrict__ off, const int2* __restrict__ csr_se,
    const float* __restrict__ el, const float* __restrict__ er,
    const unsigned short* __restrict__ ftb, const float* __restrict__ bias,
    float* __restrict__ hout, float* __restrict__ attn_out)
{
  const int wid = threadIdx.x >> 6;
  const int lane = threadIdx.x & 63;
  const int n = blockIdx.x * 4 + wid;
  if (n >= NN) return;
  const int beg = off[n], end = off[n + 1];
  const int h = lane & 7;       // head (softmax phase layout)
  const int eg = lane >> 3;     // edge-in-group
  const int h_own = lane >> 3;  // head owned in aggregation layout (cols lane*4..+3)
  const float er_v = er[(size_t)n * NH + h];

  // pass 1: softmax denominator per head
  float sum = 0.f;
  for (int g = beg; g < end; g += 8) {
    int s = g + eg;
    float wv = 0.f;
    if (s < end) {
      int sn = csr_se[s].x;
      float e = el[(size_t)sn * NH + h] + er_v;
      e = (e > 0.f) ? e : 0.2f * e;
      wv = __expf(e);
    }
    wv += __shfl_xor(wv, 8); wv += __shfl_xor(wv, 16); wv += __shfl_xor(wv, 32);
    sum += wv;
  }
  const float inv = 1.f / sum;  // unused when no edges

  // pass 2: attn write + aggregation, 8 gathers in flight
  float acc0 = 0.f, acc1 = 0.f, acc2 = 0.f, acc3 = 0.f;
  for (int g = beg; g < end; g += 8) {
    int s = g + eg;
    float a = 0.f;
    int sn = 0;
    if (s < end) {
      int2 se = csr_se[s];
      sn = se.x;
      float e = el[(size_t)sn * NH + h] + er_v;
      e = (e > 0.f) ? e : 0.2f * e;
      a = __expf(e) * inv;
      __builtin_nontemporal_store(a, attn_out + (size_t)se.y * NH + h);
    }
    ushort4 u[8];
    float av[8];
#pragma unroll
    for (int j = 0; j < 8; j++) {
      av[j] = __shfl(a, j * 8 + h_own);
      int sj = __shfl(sn, j * 8);
      u[j] = *(const ushort4*)(ftb + (size_t)sj * CT + lane * 4);
    }
#pragma unroll
    for (int j = 0; j < 8; j++) {
      acc0 += bf2f(u[j].x) * av[j];
      acc1 += bf2f(u[j].y) * av[j];
      acc2 += bf2f(u[j].z) * av[j];
      acc3 += bf2f(u[j].w) * av[j];
    }
  }

  // reduce over heads (lanes differing in bits 3..5 share the same d)
#pragma unroll
  for (int mks = 8; mks <= 32; mks <<= 1) {
    acc0 += __shfl_xor(acc0, mks);
    acc1 += __shfl_xor(acc1, mks);
    acc2 += __shfl_xor(acc2, mks);
    acc3 += __shfl_xor(acc3, mks);
  }
  if (lane < 8) {
    float b0 = 0.f, b1 = 0.f, b2 = 0.f, b3 = 0.f;
#pragma unroll
    for (int hh = 0; hh < NH; hh++) {
      const float* bp = bias + hh * 32 + lane * 4;
      b0 += bp[0]; b1 += bp[1]; b2 += bp[2]; b3 += bp[3];
    }
    float* op = hout + (size_t)n * 32 + lane * 4;
    __builtin_nontemporal_store((acc0 + b0) * 0.125f, op + 0);
    __builtin_nontemporal_store((acc1 + b1) * 0.125f, op + 1);
    __builtin_nontemporal_store((acc2 + b2) * 0.125f, op + 2);
    __builtin_nontemporal_store((acc3 + b3) * 0.125f, op + 3);
  }
}

extern "C" void kernel_launch(void* const* d_in, const int* in_sizes, int n_in,
                              void* d_out, int out_size, void* d_ws, size_t ws_size,
                              hipStream_t stream) {
  const float* feat   = (const float*)d_in[0];
  const int*   src    = (const int*)d_in[1];
  const int*   dst    = (const int*)d_in[2];
  const float* W      = (const float*)d_in[3];
  const float* attn_l = (const float*)d_in[4];
  const float* attn_r = (const float*)d_in[5];
  const float* bias   = (const float*)d_in[6];

  char* ws = (char*)d_ws;
  size_t o = 0;
  unsigned short* ftb = (unsigned short*)(ws + o); o += (size_t)NN * CT * 2;  // 51.2 MB (8-aligned end)
  int2* csr_se        = (int2*)(ws + o);           o += (size_t)NE * 8;       // 12.8 MB
  float* el           = (float*)(ws + o);          o += (size_t)NN * NH * 4;
  float* er           = (float*)(ws + o);          o += (size_t)NN * NH * 4;
  int* cnt            = (int*)(ws + o);            o += (size_t)NN * 4;
  int* off            = (int*)(ws + o);            o += (size_t)(NN + 2) * 4;
  int* cur            = (int*)(ws + o);            o += (size_t)NN * 4;
  unsigned short* Wt  = (unsigned short*)(ws + o); o += (size_t)CT * KF * 2;
  int* bsum           = (int*)(ws + o);            o += 128 * 4;
  int* bexc           = (int*)(ws + o);            o += 128 * 4;

  float* hout     = (float*)d_out;                 // NN*32
  float* attn_out = hout + (size_t)NN * 32;        // NE*8

  const int NB = (NN + 1023) / 1024;  // 98

  k_wconv<<<(KF * CT + 255) / 256, 256, 0, stream>>>(W, Wt);
  k_gemm<<<(NN + 63) / 64, 256, 0, stream>>>(feat, Wt, attn_l, attn_r, ftb, el, er);
  hipMemsetAsync(cnt, 0, NN * sizeof(int), stream);
  k_hist<<<(NE + 255) / 256, 256, 0, stream>>>(dst, cnt);
  k_scan1<<<NB, 1024, 0, stream>>>(cnt, bsum);
  k_scan2<<<1, 128, 0, stream>>>(bsum, bexc, NB);
  k_scan3<<<NB, 1024, 0, stream>>>(cnt, bexc, off, cur);
  k_scatter<<<(NE + 255) / 256, 256, 0, stream>>>(src, dst, cur, csr_se);
  k_edge<<<(NN + 3) / 4, 256, 0, stream>>>(off, csr_se, el, er, ftb, bias, hout, attn_out);
}